// Round 7
// baseline (728.302 us; speedup 1.0000x reference)
//
#include <hip/hip_runtime.h>
#include <hip/hip_bf16.h>
#include <math.h>
#include <stdint.h>

// Problem constants (CoconutPPO): B=128, H=4096, R=256, M=500000, K=3
#define BB 128
#define HH 4096
#define RR 256
#define M_TOT 500000
#define CHUNK 1024
#define NCHUNK ((M_TOT + CHUNK - 1) / CHUNK)   // 489
#define TINYF 1.17549435e-38f

// d_out layout (floats, concatenated in return order)
#define OFF_LATENT 0
#define OFF_POS    524288
#define OFF_ACT    557056
#define OFF_LP     557184
#define OFF_VAL    557312
#define OFF_ENT    557440

typedef __attribute__((ext_vector_type(8))) short bf16x8;
typedef __attribute__((ext_vector_type(4))) float f32x4;

// ---------------------------------------------------------------- helpers
__device__ __forceinline__ bool better(float a, int ia, float b, int ib) {
  return a > b || (a == b && ia < ib);
}
__device__ __forceinline__ void ins4(float s, int id, float (&vs)[4], int (&vi)[4]) {
  if (id == vi[0] || id == vi[1] || id == vi[2] || id == vi[3]) return;
  if (better(s, id, vs[3], vi[3])) {
    vs[3] = s; vi[3] = id;
    if (better(vs[3], vi[3], vs[2], vi[2])) { float a=vs[3]; vs[3]=vs[2]; vs[2]=a; int x=vi[3]; vi[3]=vi[2]; vi[2]=x; }
    if (better(vs[2], vi[2], vs[1], vi[1])) { float a=vs[2]; vs[2]=vs[1]; vs[1]=a; int x=vi[2]; vi[2]=vi[1]; vi[1]=x; }
    if (better(vs[1], vi[1], vs[0], vi[0])) { float a=vs[1]; vs[1]=vs[0]; vs[0]=a; int x=vi[1]; vi[1]=vi[0]; vi[0]=x; }
  }
}
__device__ __forceinline__ void ins3(float s, int id, float (&vs)[3], int (&vi)[3]) {
  if (id == vi[0] || id == vi[1] || id == vi[2]) return;
  if (better(s, id, vs[2], vi[2])) {
    vs[2] = s; vi[2] = id;
    if (better(vs[2], vi[2], vs[1], vi[1])) { float a=vs[2]; vs[2]=vs[1]; vs[1]=a; int x=vi[2]; vi[2]=vi[1]; vi[1]=x; }
    if (better(vs[1], vi[1], vs[0], vi[0])) { float a=vs[1]; vs[1]=vs[0]; vs[0]=a; int x=vi[1]; vi[1]=vi[0]; vi[0]=x; }
  }
}
__device__ __forceinline__ void ins8(float s, int id, float (&vs)[8], int (&vi)[8]) {
#pragma unroll
  for (int q = 0; q < 8; ++q) if (id == vi[q]) return;
  if (!better(s, id, vs[7], vi[7])) return;
  vs[7] = s; vi[7] = id;
#pragma unroll
  for (int q = 7; q > 0; --q)
    if (better(vs[q], vi[q], vs[q-1], vi[q-1])) {
      float a = vs[q]; vs[q] = vs[q-1]; vs[q-1] = a;
      int x = vi[q]; vi[q] = vi[q-1]; vi[q-1] = x;
    }
}

// RNE f32 -> bf16 (bit arithmetic; matches hardware/NumPy RNE)
__device__ __forceinline__ uint32_t rne_u(float x) {
  uint32_t u = __float_as_uint(x);
  return (u + 0x7fffu + ((u >> 16) & 1u)) >> 16;
}
// pack two f32 -> one u32 holding 2x bf16 (lo in low half)
__device__ __forceinline__ uint32_t pk_bf16(float lo, float hi) {
  return rne_u(lo) | (rne_u(hi) << 16);
}

#define TF_ROUND(r) { x0 += x1; x1 = (x1 << (r)) | (x1 >> (32 - (r))); x1 ^= x0; }
__device__ __forceinline__ void threefry2x32(uint32_t k0, uint32_t k1,
                                             uint32_t x0, uint32_t x1,
                                             uint32_t& o0, uint32_t& o1) {
  const uint32_t ks2 = k0 ^ k1 ^ 0x1BD11BDAu;
  x0 += k0; x1 += k1;
  TF_ROUND(13) TF_ROUND(15) TF_ROUND(26) TF_ROUND(6)
  x0 += k1; x1 += ks2 + 1u;
  TF_ROUND(17) TF_ROUND(29) TF_ROUND(16) TF_ROUND(24)
  x0 += ks2; x1 += k0 + 2u;
  TF_ROUND(13) TF_ROUND(15) TF_ROUND(26) TF_ROUND(6)
  x0 += k0; x1 += k1 + 3u;
  TF_ROUND(17) TF_ROUND(29) TF_ROUND(16) TF_ROUND(24)
  x0 += k1; x1 += ks2 + 4u;
  TF_ROUND(13) TF_ROUND(15) TF_ROUND(26) TF_ROUND(6)
  x0 += ks2; x1 += k0 + 5u;
  o0 = x0; o1 = x1;
}

__device__ __forceinline__ float gumbel_from_bits(uint32_t bits) {
  const uint32_t fb = (bits >> 9) | 0x3f800000u;
  const float fl = __uint_as_float(fb) - 1.0f;
  const float u = fmaxf(TINYF, fl * (1.0f - TINYF) + TINYF);
  return -logf(-logf(u));
}

// ---------------------------------------------------------------- generic fp32 GEMM (partial slabs)
// C[z][M,N] partial = A[M, k0..k0+klen] @ B[k0..,N]; 64x64 tile, 4x4/thread.
__global__ __launch_bounds__(256)
void gemm_tile(const float* __restrict__ A, const float* __restrict__ Bw,
               float* __restrict__ C, int Mr, int Nc, int K, int klen) {
  __shared__ float As[16][68];
  __shared__ float Bs[16][68];
  const int col0 = blockIdx.x * 64;
  const int row0 = blockIdx.y * 64;
  const int k0 = blockIdx.z * klen;
  const int t = threadIdx.x;
  const int tc = t & 15, tr = t >> 4;
  float acc[4][4] = {};
  for (int kk = k0; kk < k0 + klen; kk += 16) {
    {
      const int r = t >> 2, c4 = (t & 3) << 2;
      const float4 v = *reinterpret_cast<const float4*>(A + (size_t)(row0 + r) * K + kk + c4);
      As[c4 + 0][r] = v.x; As[c4 + 1][r] = v.y; As[c4 + 2][r] = v.z; As[c4 + 3][r] = v.w;
    }
    {
      const int kr = t >> 4, c4 = (t & 15) << 2;
      const float4 v = *reinterpret_cast<const float4*>(Bw + (size_t)(kk + kr) * Nc + col0 + c4);
      *reinterpret_cast<float4*>(&Bs[kr][c4]) = v;
    }
    __syncthreads();
#pragma unroll
    for (int k = 0; k < 16; ++k) {
      const float4 a4 = *reinterpret_cast<const float4*>(&As[k][tr * 4]);
      const float4 b4 = *reinterpret_cast<const float4*>(&Bs[k][tc * 4]);
      float a[4] = {a4.x, a4.y, a4.z, a4.w};
      float b[4] = {b4.x, b4.y, b4.z, b4.w};
#pragma unroll
      for (int i = 0; i < 4; ++i)
#pragma unroll
        for (int j = 0; j < 4; ++j) acc[i][j] += a[i] * b[j];
    }
    __syncthreads();
  }
  float* Cp = C + (size_t)blockIdx.z * Mr * Nc;
#pragma unroll
  for (int i = 0; i < 4; ++i) {
    const int row = row0 + tr * 4 + i;
#pragma unroll
    for (int j = 0; j < 4; ++j) {
      Cp[(size_t)row * Nc + col0 + tc * 4 + j] = acc[i][j];
    }
  }
}

// ---------------------------------------------------------------- combines
template<int Z, bool RELU>
__global__ void combine_z(const float* __restrict__ src, const float* __restrict__ bias,
                          float* __restrict__ dst, int total, int mask) {
  const int i = blockIdx.x * 256 + threadIdx.x;
  float v = bias[i & mask];
#pragma unroll
  for (int z = 0; z < Z; ++z) v += src[(size_t)z * total + i];
  dst[i] = RELU ? fmaxf(v, 0.0f) : v;
}

__global__ __launch_bounds__(256)
void combine_r0(const float* __restrict__ r0p, const float* __restrict__ b2,
                float* __restrict__ r0, float* __restrict__ rnorm) {
  const int b = blockIdx.x, t = threadIdx.x;
  __shared__ float red[256];
  float v = b2[t];
#pragma unroll
  for (int z = 0; z < 8; ++z) v += r0p[z * 32768 + b * 256 + t];
  r0[b * 256 + t] = v;
  red[t] = v * v;
  __syncthreads();
  for (int s = 128; s > 0; s >>= 1) { if (t < s) red[t] += red[t + s]; __syncthreads(); }
  const float inv = 1.0f / fmaxf(sqrtf(red[0]), 1e-12f);
  rnorm[b * 256 + t] = v * inv;
}

// ---------------------------------------------------------------- MFMA sims + per-chunk top-4
// 512 thr / 8 waves. Chunk = 1024 mem rows = 8 subs of 128.
// rnorm B-frags (bf16) in registers (loaded once). Bank sub-tile staged
// fp32->bf16 into a 64KB XOR-swizzled LDS tile.
// PIPELINE (T14): sub+1's 16 float4 bank loads are issued into registers right
// after the "tile ready" barrier, staying in flight across the MFMA phase.
__global__ __launch_bounds__(512, 4)
void sims_topk(const float* __restrict__ rnorm, const float* __restrict__ bank,
               const float* __restrict__ vals, float* __restrict__ cand_s,
               int* __restrict__ cand_i) {
  __shared__ __align__(16) unsigned short tA[128 * 256];   // 64 KB
  __shared__ float wscaleL[128];

  const int t = threadIdx.x;
  const int lane = t & 63;
  const int w = t >> 6;            // wave -> batch tile (16 rows)
  const int fr = lane & 15;
  const int fq = lane >> 4;        // 0..3 (k-group)
  const int sr = t >> 2;           // staging row 0..127
  const int sq = t & 3;            // staging 64-float quarter

  // ---- B-frags: rnorm[w*16+fr][ks*32 + fq*8 .. +8], bf16, in registers
  bf16x8 Bf[8];
  {
    const float* rp = rnorm + (size_t)(w * 16 + fr) * 256 + fq * 8;
#pragma unroll
    for (int ks = 0; ks < 8; ++ks) {
      const float4 x0 = *reinterpret_cast<const float4*>(rp + ks * 32);
      const float4 x1 = *reinterpret_cast<const float4*>(rp + ks * 32 + 4);
      uint4 pk;
      pk.x = pk_bf16(x0.x, x0.y);
      pk.y = pk_bf16(x0.z, x0.w);
      pk.z = pk_bf16(x1.x, x1.y);
      pk.w = pk_bf16(x1.z, x1.w);
      Bf[ks] = *reinterpret_cast<bf16x8*>(&pk);
    }
  }

  float ts[4]; int ti[4];
#pragma unroll
  for (int q = 0; q < 4; ++q) { ts[q] = -INFINITY; ti[q] = 0x7ffffff0 + q; }

  // prefetch registers (live across the MFMA phase)
  float4 pf[16];
  float pv;

  // issue loads for a sub (no math, just VMEM issue + zero-fill OOB)
  auto issue = [&](int sub) {
    const int m = blockIdx.x * CHUNK + sub * 128 + sr;
    if (m < M_TOT) {
      const float4* src = reinterpret_cast<const float4*>(bank + (size_t)m * 256 + sq * 64);
#pragma unroll
      for (int i = 0; i < 16; ++i) pf[i] = src[i];
      pv = (sq == 0) ? vals[m] : 0.0f;
    } else {
#pragma unroll
      for (int i = 0; i < 16; ++i) pf[i] = make_float4(0.f, 0.f, 0.f, 0.f);
      pv = 0.0f;
    }
  };

  issue(0);

  for (int sub = 0; sub < 8; ++sub) {
    const int m_base = blockIdx.x * CHUNK + sub * 128;
    // ---- convert prefetched rows -> bf16 LDS tile (+ row sumsq)
    float rs = 0.0f;
#pragma unroll
    for (int r = 0; r < 4; ++r) {
      const float4 v0 = pf[4 * r], v1 = pf[4 * r + 1], v2 = pf[4 * r + 2], v3 = pf[4 * r + 3];
      rs += v0.x*v0.x + v0.y*v0.y + v0.z*v0.z + v0.w*v0.w
          + v1.x*v1.x + v1.y*v1.y + v1.z*v1.z + v1.w*v1.w
          + v2.x*v2.x + v2.y*v2.y + v2.z*v2.z + v2.w*v2.w
          + v3.x*v3.x + v3.y*v3.y + v3.z*v3.z + v3.w*v3.w;
      uint4 pA, pB;
      pA.x = pk_bf16(v0.x, v0.y); pA.y = pk_bf16(v0.z, v0.w);
      pA.z = pk_bf16(v1.x, v1.y); pA.w = pk_bf16(v1.z, v1.w);
      pB.x = pk_bf16(v2.x, v2.y); pB.y = pk_bf16(v2.z, v2.w);
      pB.z = pk_bf16(v3.x, v3.y); pB.w = pk_bf16(v3.z, v3.w);
      const int c0 = sq * 8 + r * 2;   // 16B chunk index (0..31)
      *reinterpret_cast<uint4*>(tA + sr * 256 + ((c0 ^ (sr & 7)) << 3)) = pA;
      *reinterpret_cast<uint4*>(tA + sr * 256 + (((c0 + 1) ^ (sr & 7)) << 3)) = pB;
    }
    rs += __shfl_xor(rs, 1);
    rs += __shfl_xor(rs, 2);
    if (sq == 0) wscaleL[sr] = (pv + 1e-8f) / fmaxf(sqrtf(rs), 1e-12f);
    __syncthreads();                   // tile + wscale ready

    // ---- issue next sub's loads NOW: in flight across MFMA + epilogue
    if (sub + 1 < 8) issue(sub + 1);

    // ---- MFMA phase
    f32x4 acc[8];
#pragma unroll
    for (int mt = 0; mt < 8; ++mt) acc[mt] = (f32x4){0.f, 0.f, 0.f, 0.f};
#pragma unroll
    for (int ks = 0; ks < 8; ++ks) {
      const int kc = ks * 4 + fq;
#pragma unroll
      for (int mt = 0; mt < 8; ++mt) {
        const int rA = mt * 16 + fr;
        const bf16x8 a = *reinterpret_cast<const bf16x8*>(tA + rA * 256 + ((kc ^ (rA & 7)) << 3));
        acc[mt] = __builtin_amdgcn_mfma_f32_16x16x32_bf16(a, Bf[ks], acc[mt], 0, 0, 0);
      }
    }
    // ---- epilogue: weighted scores -> per-lane top-4 (batch row w*16+fr)
#pragma unroll
    for (int mt = 0; mt < 8; ++mt) {
#pragma unroll
      for (int j = 0; j < 4; ++j) {
        const int ml = mt * 16 + fq * 4 + j;
        const int mm = m_base + ml;
        if (mm < M_TOT) ins4(acc[mt][j] * wscaleL[ml], mm, ts, ti);
      }
    }
    __syncthreads();                   // done with tA before restage
  }

  // merge the 4 fq-lane groups sharing each batch row (snapshot butterfly)
#pragma unroll
  for (int mask = 16; mask < 64; mask <<= 1) {
    float os[4]; int oi[4];
#pragma unroll
    for (int q = 0; q < 4; ++q) {
      os[q] = __shfl_xor(ts[q], mask);
      oi[q] = __shfl_xor(ti[q], mask);
    }
#pragma unroll
    for (int q = 0; q < 4; ++q) ins4(os[q], oi[q], ts, ti);
  }
  if (fq == 0) {
    const int b = w * 16 + fr;
    const size_t base = ((size_t)b * NCHUNK + blockIdx.x) * 4;
#pragma unroll
    for (int q = 0; q < 4; ++q) { cand_s[base + q] = ts[q]; cand_i[base + q] = ti[q]; }
  }
}

// ---------------------------------------------------------------- global merge: approx top-8 -> exact rescore -> top-3 -> fuse
__global__ __launch_bounds__(256)
void topk_merge_fuse(const float* __restrict__ cand_s, const int* __restrict__ cand_i,
                     const float* __restrict__ bank, const float* __restrict__ vals,
                     const float* __restrict__ rnorm, const float* __restrict__ r0,
                     float* __restrict__ rfused) {
  const int b = blockIdx.x, t = threadIdx.x;
  __shared__ float rnL[256];
  __shared__ float ss[2048];
  __shared__ int   si[2048];
  __shared__ int   g8[8];
  __shared__ float sc8[8];
  __shared__ int   gidx[3];

  rnL[t] = rnorm[b * 256 + t];

  float ts[8]; int ti[8];
#pragma unroll
  for (int q = 0; q < 8; ++q) { ts[q] = -INFINITY; ti[q] = 0x7fffff00 + t * 8 + q; }
  const int n = NCHUNK * 4;
  const size_t base = (size_t)b * n;
  for (int c = t; c < n; c += 256) ins8(cand_s[base + c], cand_i[base + c], ts, ti);
#pragma unroll
  for (int q = 0; q < 8; ++q) { ss[t * 8 + q] = ts[q]; si[t * 8 + q] = ti[q]; }
  __syncthreads();

  if (t < 64) {
    float ms[8]; int mi[8];
#pragma unroll
    for (int q = 0; q < 8; ++q) { ms[q] = -INFINITY; mi[q] = 0x7ffffe00 + t * 8 + q; }
    for (int c = t * 32; c < t * 32 + 32; ++c) ins8(ss[c], si[c], ms, mi);
#pragma unroll
    for (int mask = 1; mask < 64; mask <<= 1) {
      float os[8]; int oi[8];
#pragma unroll
      for (int q = 0; q < 8; ++q) { os[q] = __shfl_xor(ms[q], mask); oi[q] = __shfl_xor(mi[q], mask); }
#pragma unroll
      for (int q = 0; q < 8; ++q) ins8(os[q], oi[q], ms, mi);
    }
    if (t == 0) {
#pragma unroll
      for (int q = 0; q < 8; ++q) g8[q] = mi[q];
    }
  }
  __syncthreads();

  {
    const int c = t >> 5, g = t & 31;
    const int id = g8[c];
    float ssq = 0.0f, dt = 0.0f;
    if (id < M_TOT) {
      const float4* bp = reinterpret_cast<const float4*>(bank + (size_t)id * 256);
      const float4 x0 = bp[g * 2], x1 = bp[g * 2 + 1];
      const float4 r0v = *reinterpret_cast<const float4*>(&rnL[g * 8]);
      const float4 r1v = *reinterpret_cast<const float4*>(&rnL[g * 8 + 4]);
      ssq = x0.x*x0.x + x0.y*x0.y + x0.z*x0.z + x0.w*x0.w +
            x1.x*x1.x + x1.y*x1.y + x1.z*x1.z + x1.w*x1.w;
      dt  = x0.x*r0v.x + x0.y*r0v.y + x0.z*r0v.z + x0.w*r0v.w +
            x1.x*r1v.x + x1.y*r1v.y + x1.z*r1v.z + x1.w*r1v.w;
    }
#pragma unroll
    for (int mask = 1; mask < 32; mask <<= 1) { ssq += __shfl_xor(ssq, mask); dt += __shfl_xor(dt, mask); }
    if (g == 0)
      sc8[c] = (id < M_TOT)
                 ? dt * (1.0f / fmaxf(sqrtf(ssq), 1e-12f)) * (vals[id] + 1e-8f)
                 : -INFINITY;
  }
  __syncthreads();

  if (t == 0) {
    float gs[3] = {-INFINITY, -INFINITY, -INFINITY};
    int gi[3] = {0x7fffffff, 0x7ffffffe, 0x7ffffffd};
#pragma unroll
    for (int q = 0; q < 8; ++q) ins3(sc8[q], g8[q], gs, gi);
    gidx[0] = gi[0]; gidx[1] = gi[1]; gidx[2] = gi[2];
  }
  __syncthreads();

  const int i0 = gidx[0], i1 = gidx[1], i2 = gidx[2];
  const float retr = (bank[(size_t)i0 * 256 + t] + bank[(size_t)i1 * 256 + t] +
                      bank[(size_t)i2 * 256 + t]) / 3.0f;
  rfused[b * 256 + t] = 0.5f * r0[b * 256 + t] + 0.5f * retr;
}

// ---------------------------------------------------------------- policy heads (+threefry categorical)
__global__ __launch_bounds__(256)
void heads(const float* __restrict__ rf, const float* __restrict__ Wc, const float* __restrict__ bc,
           const float* __restrict__ Wd, const float* __restrict__ bd,
           const float* __restrict__ Wsw, const float* __restrict__ bsw,
           const float* __restrict__ Wv, const float* __restrict__ bv,
           float* __restrict__ out) {
  const int b = blockIdx.x, t = threadIdx.x;
  __shared__ float rl[256];
  __shared__ float red[256];
  __shared__ float hd[8];
  rl[t] = rf[b * 256 + t];
  __syncthreads();
  float y = bd[t];
#pragma unroll 8
  for (int k = 0; k < 256; ++k) y += rl[k] * Wd[k * 256 + t];
  red[t] = y * y;
  if (t < 4) {
    float a;
    if (t == 0) { a = bc[0]; for (int k = 0; k < 256; ++k) a += rl[k] * Wc[2 * k]; }
    else if (t == 1) { a = bc[1]; for (int k = 0; k < 256; ++k) a += rl[k] * Wc[2 * k + 1]; }
    else if (t == 2) { a = bsw[0]; for (int k = 0; k < 256; ++k) a += rl[k] * Wsw[k]; }
    else { a = bv[0]; for (int k = 0; k < 256; ++k) a += rl[k] * Wv[k]; }
    hd[t] = a;
  }
  __syncthreads();
  for (int s = 128; s > 0; s >>= 1) { if (t < s) red[t] += red[t + s]; __syncthreads(); }
  const float dirn = y / fmaxf(sqrtf(red[0]), 1e-12f);
  if (t == 0) {
    const float l0 = hd[0], l1 = hd[1];
    uint32_t a0, a1, c0, c1;
    threefry2x32(0u, 1u, 0u, (uint32_t)(2 * b), a0, a1);
    threefry2x32(0u, 1u, 0u, (uint32_t)(2 * b + 1), c0, c1);
    const float g0 = gumbel_from_bits(a0 ^ a1);
    const float g1 = gumbel_from_bits(c0 ^ c1);
    const int act = (l1 + g1 > l0 + g0) ? 1 : 0;
    const float mx = fmaxf(l0, l1);
    const float lse = mx + logf(expf(l0 - mx) + expf(l1 - mx));
    const float lp0 = l0 - lse, lp1 = l1 - lse;
    out[OFF_ACT + b] = (float)act;
    out[OFF_LP + b] = act ? lp1 : lp0;
    out[OFF_VAL + b] = hd[3];
    out[OFF_ENT + b] = -(expf(lp0) * lp0 + expf(lp1) * lp1);
    hd[4] = 2.0f / (1.0f + expf(-hd[2]));
  }
  __syncthreads();
  out[OFF_POS + b * 256 + t] = rl[t] + hd[4] * dirn;
}

// ---------------------------------------------------------------- launch
extern "C" void kernel_launch(void* const* d_in, const int* in_sizes, int n_in,
                              void* d_out, int out_size, void* d_ws, size_t ws_size,
                              hipStream_t stream) {
  const float* state = (const float*)d_in[0];
  const float* bank  = (const float*)d_in[1];
  const float* vals  = (const float*)d_in[2];
  const float* W1  = (const float*)d_in[3];
  const float* b1  = (const float*)d_in[4];
  const float* W2  = (const float*)d_in[5];
  const float* b2  = (const float*)d_in[6];
  const float* Wc  = (const float*)d_in[7];
  const float* bc  = (const float*)d_in[8];
  const float* Wd  = (const float*)d_in[9];
  const float* bd  = (const float*)d_in[10];
  const float* Wsw = (const float*)d_in[11];
  const float* bsw = (const float*)d_in[12];
  const float* Wv  = (const float*)d_in[13];
  const float* bv  = (const float*)d_in[14];
  const float* T1w = (const float*)d_in[15];
  const float* t1b = (const float*)d_in[16];
  const float* T2w = (const float*)d_in[17];
  const float* t2b = (const float*)d_in[18];
  float* out = (float*)d_out;
  float* ws = (float*)d_ws;

  // workspace layout (floats) with region reuse:
  float* regA = ws;                   // 1048576: W1 partials (8x131072) then T2 partials (2x524288)
  float* h1   = ws + 1048576;         // 131072
  float* regC = ws + 1179648;         // 262144: W2 partials (8x32768) then T1 partials (2x131072)
  float* r0   = ws + 1441792;         // 32768
  float* rnm  = ws + 1474560;         // 32768
  float* cs   = ws + 1507328;         // 250368 (128*489*4)
  int*   ci   = (int*)(ws + 1757696); // 250368
  float* rf   = ws + 2008064;         // 32768
  float* h2   = ws + 2040832;         // 131072

  // state_projection: H -> H/4 (relu) -> R
  gemm_tile<<<dim3(16, 2, 8), 256, 0, stream>>>(state, W1, regA, 128, 1024, 4096, 512);
  combine_z<8, true><<<512, 256, 0, stream>>>(regA, b1, h1, 131072, 1023);
  gemm_tile<<<dim3(4, 2, 8), 256, 0, stream>>>(h1, W2, regC, 128, 256, 1024, 128);
  combine_r0<<<128, 256, 0, stream>>>(regC, b2, r0, rnm);
  // retrieval: MFMA approx sims + per-chunk top-4, then exact-rescore merge + fuse
  sims_topk<<<NCHUNK, 512, 0, stream>>>(rnm, bank, vals, cs, ci);
  topk_merge_fuse<<<128, 256, 0, stream>>>(cs, ci, bank, vals, rnm, r0, rf);
  // policy heads + position
  heads<<<128, 256, 0, stream>>>(rf, Wc, bc, Wd, bd, Wsw, bsw, Wv, bv, out);
  // thought_projection: R -> H/4 (relu) -> H
  gemm_tile<<<dim3(16, 2, 2), 256, 0, stream>>>(out + OFF_POS, T1w, regC, 128, 1024, 256, 128);
  combine_z<2, true><<<512, 256, 0, stream>>>(regC, t1b, h2, 131072, 1023);
  gemm_tile<<<dim3(64, 2, 2), 256, 0, stream>>>(h2, T2w, regA, 128, 4096, 1024, 512);
  combine_z<2, false><<<2048, 256, 0, stream>>>(regA, t2b, out + OFF_LATENT, 524288, 4095);
}

// Round 8
// 452.701 us; speedup vs baseline: 1.6088x; 1.6088x over previous
//
#include <hip/hip_runtime.h>
#include <hip/hip_bf16.h>
#include <math.h>
#include <stdint.h>

// Problem constants (CoconutPPO): B=128, H=4096, R=256, M=500000, K=3
#define BB 128
#define HH 4096
#define RR 256
#define M_TOT 500000
#define CHUNK 512
#define NCHUNK ((M_TOT + CHUNK - 1) / CHUNK)   // 977
#define TINYF 1.17549435e-38f

// d_out layout (floats, concatenated in return order)
#define OFF_LATENT 0
#define OFF_POS    524288
#define OFF_ACT    557056
#define OFF_LP     557184
#define OFF_VAL    557312
#define OFF_ENT    557440

typedef __attribute__((ext_vector_type(8))) short bf16x8;
typedef __attribute__((ext_vector_type(4))) float f32x4;

// ---------------------------------------------------------------- helpers
__device__ __forceinline__ bool better(float a, int ia, float b, int ib) {
  return a > b || (a == b && ia < ib);
}
__device__ __forceinline__ void ins4(float s, int id, float (&vs)[4], int (&vi)[4]) {
  if (id == vi[0] || id == vi[1] || id == vi[2] || id == vi[3]) return;
  if (better(s, id, vs[3], vi[3])) {
    vs[3] = s; vi[3] = id;
    if (better(vs[3], vi[3], vs[2], vi[2])) { float a=vs[3]; vs[3]=vs[2]; vs[2]=a; int x=vi[3]; vi[3]=vi[2]; vi[2]=x; }
    if (better(vs[2], vi[2], vs[1], vi[1])) { float a=vs[2]; vs[2]=vs[1]; vs[1]=a; int x=vi[2]; vi[2]=vi[1]; vi[1]=x; }
    if (better(vs[1], vi[1], vs[0], vi[0])) { float a=vs[1]; vs[1]=vs[0]; vs[0]=a; int x=vi[1]; vi[1]=vi[0]; vi[0]=x; }
  }
}
__device__ __forceinline__ void ins3(float s, int id, float (&vs)[3], int (&vi)[3]) {
  if (id == vi[0] || id == vi[1] || id == vi[2]) return;
  if (better(s, id, vs[2], vi[2])) {
    vs[2] = s; vi[2] = id;
    if (better(vs[2], vi[2], vs[1], vi[1])) { float a=vs[2]; vs[2]=vs[1]; vs[1]=a; int x=vi[2]; vi[2]=vi[1]; vi[1]=x; }
    if (better(vs[1], vi[1], vs[0], vi[0])) { float a=vs[1]; vs[1]=vs[0]; vs[0]=a; int x=vi[1]; vi[1]=vi[0]; vi[0]=x; }
  }
}
__device__ __forceinline__ void ins8(float s, int id, float (&vs)[8], int (&vi)[8]) {
#pragma unroll
  for (int q = 0; q < 8; ++q) if (id == vi[q]) return;
  if (!better(s, id, vs[7], vi[7])) return;
  vs[7] = s; vi[7] = id;
#pragma unroll
  for (int q = 7; q > 0; --q)
    if (better(vs[q], vi[q], vs[q-1], vi[q-1])) {
      float a = vs[q]; vs[q] = vs[q-1]; vs[q-1] = a;
      int x = vi[q]; vi[q] = vi[q-1]; vi[q-1] = x;
    }
}

// RNE f32 -> bf16 (bit arithmetic; matches hardware/NumPy RNE)
__device__ __forceinline__ uint32_t rne_u(float x) {
  uint32_t u = __float_as_uint(x);
  return (u + 0x7fffu + ((u >> 16) & 1u)) >> 16;
}
// pack two f32 -> one u32 holding 2x bf16 (lo in low half)
__device__ __forceinline__ uint32_t pk_bf16(float lo, float hi) {
  return rne_u(lo) | (rne_u(hi) << 16);
}

#define TF_ROUND(r) { x0 += x1; x1 = (x1 << (r)) | (x1 >> (32 - (r))); x1 ^= x0; }
__device__ __forceinline__ void threefry2x32(uint32_t k0, uint32_t k1,
                                             uint32_t x0, uint32_t x1,
                                             uint32_t& o0, uint32_t& o1) {
  const uint32_t ks2 = k0 ^ k1 ^ 0x1BD11BDAu;
  x0 += k0; x1 += k1;
  TF_ROUND(13) TF_ROUND(15) TF_ROUND(26) TF_ROUND(6)
  x0 += k1; x1 += ks2 + 1u;
  TF_ROUND(17) TF_ROUND(29) TF_ROUND(16) TF_ROUND(24)
  x0 += ks2; x1 += k0 + 2u;
  TF_ROUND(13) TF_ROUND(15) TF_ROUND(26) TF_ROUND(6)
  x0 += k0; x1 += k1 + 3u;
  TF_ROUND(17) TF_ROUND(29) TF_ROUND(16) TF_ROUND(24)
  x0 += k1; x1 += ks2 + 4u;
  TF_ROUND(13) TF_ROUND(15) TF_ROUND(26) TF_ROUND(6)
  x0 += ks2; x1 += k0 + 5u;
  o0 = x0; o1 = x1;
}

__device__ __forceinline__ float gumbel_from_bits(uint32_t bits) {
  const uint32_t fb = (bits >> 9) | 0x3f800000u;
  const float fl = __uint_as_float(fb) - 1.0f;
  const float u = fmaxf(TINYF, fl * (1.0f - TINYF) + TINYF);
  return -logf(-logf(u));
}

// ---------------------------------------------------------------- generic fp32 GEMM (partial slabs)
// C[z][M,N] partial = A[M, k0..k0+klen] @ B[k0..,N]; 64x64 tile, 4x4/thread.
__global__ __launch_bounds__(256)
void gemm_tile(const float* __restrict__ A, const float* __restrict__ Bw,
               float* __restrict__ C, int Mr, int Nc, int K, int klen) {
  __shared__ float As[16][68];
  __shared__ float Bs[16][68];
  const int col0 = blockIdx.x * 64;
  const int row0 = blockIdx.y * 64;
  const int k0 = blockIdx.z * klen;
  const int t = threadIdx.x;
  const int tc = t & 15, tr = t >> 4;
  float acc[4][4] = {};
  for (int kk = k0; kk < k0 + klen; kk += 16) {
    {
      const int r = t >> 2, c4 = (t & 3) << 2;
      const float4 v = *reinterpret_cast<const float4*>(A + (size_t)(row0 + r) * K + kk + c4);
      As[c4 + 0][r] = v.x; As[c4 + 1][r] = v.y; As[c4 + 2][r] = v.z; As[c4 + 3][r] = v.w;
    }
    {
      const int kr = t >> 4, c4 = (t & 15) << 2;
      const float4 v = *reinterpret_cast<const float4*>(Bw + (size_t)(kk + kr) * Nc + col0 + c4);
      *reinterpret_cast<float4*>(&Bs[kr][c4]) = v;
    }
    __syncthreads();
#pragma unroll
    for (int k = 0; k < 16; ++k) {
      const float4 a4 = *reinterpret_cast<const float4*>(&As[k][tr * 4]);
      const float4 b4 = *reinterpret_cast<const float4*>(&Bs[k][tc * 4]);
      float a[4] = {a4.x, a4.y, a4.z, a4.w};
      float b[4] = {b4.x, b4.y, b4.z, b4.w};
#pragma unroll
      for (int i = 0; i < 4; ++i)
#pragma unroll
        for (int j = 0; j < 4; ++j) acc[i][j] += a[i] * b[j];
    }
    __syncthreads();
  }
  float* Cp = C + (size_t)blockIdx.z * Mr * Nc;
#pragma unroll
  for (int i = 0; i < 4; ++i) {
    const int row = row0 + tr * 4 + i;
#pragma unroll
    for (int j = 0; j < 4; ++j) {
      Cp[(size_t)row * Nc + col0 + tc * 4 + j] = acc[i][j];
    }
  }
}

// ---------------------------------------------------------------- combines
template<int Z, bool RELU>
__global__ void combine_z(const float* __restrict__ src, const float* __restrict__ bias,
                          float* __restrict__ dst, int total, int mask) {
  const int i = blockIdx.x * 256 + threadIdx.x;
  float v = bias[i & mask];
#pragma unroll
  for (int z = 0; z < Z; ++z) v += src[(size_t)z * total + i];
  dst[i] = RELU ? fmaxf(v, 0.0f) : v;
}

__global__ __launch_bounds__(256)
void combine_r0(const float* __restrict__ r0p, const float* __restrict__ b2,
                float* __restrict__ r0, float* __restrict__ rnorm) {
  const int b = blockIdx.x, t = threadIdx.x;
  __shared__ float red[256];
  float v = b2[t];
#pragma unroll
  for (int z = 0; z < 8; ++z) v += r0p[z * 32768 + b * 256 + t];
  r0[b * 256 + t] = v;
  red[t] = v * v;
  __syncthreads();
  for (int s = 128; s > 0; s >>= 1) { if (t < s) red[t] += red[t + s]; __syncthreads(); }
  const float inv = 1.0f / fmaxf(sqrtf(red[0]), 1e-12f);
  rnorm[b * 256 + t] = v * inv;
}

// ---------------------------------------------------------------- MFMA sims + per-chunk top-4
// 256 thr / 4 waves, 32 KB LDS -> 4 blocks/CU: TLP hides HBM latency
// (independent blocks anti-phase their stage and MFMA phases).
// Chunk = 512 mem rows = 8 subs of 64. Each wave carries TWO batch sets
// (Bf[2][8]); one LDS A-load feeds two MFMAs.
__global__ __launch_bounds__(256)
void sims_topk(const float* __restrict__ rnorm, const float* __restrict__ bank,
               const float* __restrict__ vals, float* __restrict__ cand_s,
               int* __restrict__ cand_i) {
  __shared__ __align__(16) unsigned short tA[64 * 256];   // 32 KB
  __shared__ float wscaleL[64];

  const int t = threadIdx.x;
  const int lane = t & 63;
  const int w = t >> 6;            // wave 0..3
  const int fr = lane & 15;
  const int fq = lane >> 4;        // 0..3 (k-group)
  const int sr = t >> 2;           // staging row 0..63
  const int sq = t & 3;            // staging 64-float quarter

  // ---- B-frags for 2 batch sets: row = set*64 + w*16 + fr
  bf16x8 Bf[2][8];
#pragma unroll
  for (int set = 0; set < 2; ++set) {
    const float* rp = rnorm + (size_t)(set * 64 + w * 16 + fr) * 256 + fq * 8;
#pragma unroll
    for (int ks = 0; ks < 8; ++ks) {
      const float4 x0 = *reinterpret_cast<const float4*>(rp + ks * 32);
      const float4 x1 = *reinterpret_cast<const float4*>(rp + ks * 32 + 4);
      uint4 pk;
      pk.x = pk_bf16(x0.x, x0.y);
      pk.y = pk_bf16(x0.z, x0.w);
      pk.z = pk_bf16(x1.x, x1.y);
      pk.w = pk_bf16(x1.z, x1.w);
      Bf[set][ks] = *reinterpret_cast<bf16x8*>(&pk);
    }
  }

  float ts[2][4]; int ti[2][4];
#pragma unroll
  for (int set = 0; set < 2; ++set)
#pragma unroll
    for (int q = 0; q < 4; ++q) { ts[set][q] = -INFINITY; ti[set][q] = 0x7ffffff0 + q; }

  for (int sub = 0; sub < 8; ++sub) {
    const int m_base = blockIdx.x * CHUNK + sub * 64;
    const int m = m_base + sr;
    float vv = 0.0f;
    if (sq == 0 && m < M_TOT) vv = vals[m];
    float rs = 0.0f;
    // stage: this thread's 64 floats = bank[m][sq*64 .. +64] -> bf16 LDS
#pragma unroll
    for (int r = 0; r < 4; ++r) {
      float4 v0, v1, v2, v3;
      if (m < M_TOT) {
        const float4* src = reinterpret_cast<const float4*>(bank + (size_t)m * 256 + sq * 64 + r * 16);
        v0 = src[0]; v1 = src[1]; v2 = src[2]; v3 = src[3];
      } else {
        v0 = v1 = v2 = v3 = make_float4(0.f, 0.f, 0.f, 0.f);
      }
      rs += v0.x*v0.x + v0.y*v0.y + v0.z*v0.z + v0.w*v0.w
          + v1.x*v1.x + v1.y*v1.y + v1.z*v1.z + v1.w*v1.w
          + v2.x*v2.x + v2.y*v2.y + v2.z*v2.z + v2.w*v2.w
          + v3.x*v3.x + v3.y*v3.y + v3.z*v3.z + v3.w*v3.w;
      uint4 pA, pB;
      pA.x = pk_bf16(v0.x, v0.y); pA.y = pk_bf16(v0.z, v0.w);
      pA.z = pk_bf16(v1.x, v1.y); pA.w = pk_bf16(v1.z, v1.w);
      pB.x = pk_bf16(v2.x, v2.y); pB.y = pk_bf16(v2.z, v2.w);
      pB.z = pk_bf16(v3.x, v3.y); pB.w = pk_bf16(v3.z, v3.w);
      const int c0 = sq * 8 + r * 2;   // 16B chunk index (0..31)
      *reinterpret_cast<uint4*>(tA + sr * 256 + ((c0 ^ (sr & 7)) << 3)) = pA;
      *reinterpret_cast<uint4*>(tA + sr * 256 + (((c0 + 1) ^ (sr & 7)) << 3)) = pB;
    }
    rs += __shfl_xor(rs, 1);
    rs += __shfl_xor(rs, 2);
    if (sq == 0) wscaleL[sr] = (vv + 1e-8f) / fmaxf(sqrtf(rs), 1e-12f);
    __syncthreads();                   // tile + wscale ready

    // ---- MFMA phase: 64 mem rows x 128 batch rows
    f32x4 acc[2][4];
#pragma unroll
    for (int set = 0; set < 2; ++set)
#pragma unroll
      for (int mt = 0; mt < 4; ++mt) acc[set][mt] = (f32x4){0.f, 0.f, 0.f, 0.f};
#pragma unroll
    for (int ks = 0; ks < 8; ++ks) {
      const int kc = ks * 4 + fq;
#pragma unroll
      for (int mt = 0; mt < 4; ++mt) {
        const int rA = mt * 16 + fr;
        const bf16x8 a = *reinterpret_cast<const bf16x8*>(tA + rA * 256 + ((kc ^ (rA & 7)) << 3));
        acc[0][mt] = __builtin_amdgcn_mfma_f32_16x16x32_bf16(a, Bf[0][ks], acc[0][mt], 0, 0, 0);
        acc[1][mt] = __builtin_amdgcn_mfma_f32_16x16x32_bf16(a, Bf[1][ks], acc[1][mt], 0, 0, 0);
      }
    }
    // ---- epilogue: weighted scores -> per-lane top-4
#pragma unroll
    for (int set = 0; set < 2; ++set)
#pragma unroll
      for (int mt = 0; mt < 4; ++mt)
#pragma unroll
        for (int j = 0; j < 4; ++j) {
          const int ml = mt * 16 + fq * 4 + j;
          const int mm = m_base + ml;
          if (mm < M_TOT) ins4(acc[set][mt][j] * wscaleL[ml], mm, ts[set], ti[set]);
        }
    __syncthreads();                   // done with tA before restage
  }

  // merge the 4 fq-lane groups sharing each batch row (snapshot butterfly)
#pragma unroll
  for (int mask = 16; mask < 64; mask <<= 1) {
#pragma unroll
    for (int set = 0; set < 2; ++set) {
      float os[4]; int oi[4];
#pragma unroll
      for (int q = 0; q < 4; ++q) {
        os[q] = __shfl_xor(ts[set][q], mask);
        oi[q] = __shfl_xor(ti[set][q], mask);
      }
#pragma unroll
      for (int q = 0; q < 4; ++q) ins4(os[q], oi[q], ts[set], ti[set]);
    }
  }
  if (fq == 0) {
#pragma unroll
    for (int set = 0; set < 2; ++set) {
      const int b = set * 64 + w * 16 + fr;
      const size_t base = ((size_t)b * NCHUNK + blockIdx.x) * 4;
#pragma unroll
      for (int q = 0; q < 4; ++q) { cand_s[base + q] = ts[set][q]; cand_i[base + q] = ti[set][q]; }
    }
  }
}

// ---------------------------------------------------------------- global merge: approx top-8 -> exact rescore -> top-3 -> fuse
__global__ __launch_bounds__(256)
void topk_merge_fuse(const float* __restrict__ cand_s, const int* __restrict__ cand_i,
                     const float* __restrict__ bank, const float* __restrict__ vals,
                     const float* __restrict__ rnorm, const float* __restrict__ r0,
                     float* __restrict__ rfused) {
  const int b = blockIdx.x, t = threadIdx.x;
  __shared__ float rnL[256];
  __shared__ float ss[2048];
  __shared__ int   si[2048];
  __shared__ int   g8[8];
  __shared__ float sc8[8];
  __shared__ int   gidx[3];

  rnL[t] = rnorm[b * 256 + t];

  float ts[8]; int ti[8];
#pragma unroll
  for (int q = 0; q < 8; ++q) { ts[q] = -INFINITY; ti[q] = 0x7fffff00 + t * 8 + q; }
  const int n = NCHUNK * 4;
  const size_t base = (size_t)b * n;
  for (int c = t; c < n; c += 256) ins8(cand_s[base + c], cand_i[base + c], ts, ti);
#pragma unroll
  for (int q = 0; q < 8; ++q) { ss[t * 8 + q] = ts[q]; si[t * 8 + q] = ti[q]; }
  __syncthreads();

  if (t < 64) {
    float ms[8]; int mi[8];
#pragma unroll
    for (int q = 0; q < 8; ++q) { ms[q] = -INFINITY; mi[q] = 0x7ffffe00 + t * 8 + q; }
    for (int c = t * 32; c < t * 32 + 32; ++c) ins8(ss[c], si[c], ms, mi);
#pragma unroll
    for (int mask = 1; mask < 64; mask <<= 1) {
      float os[8]; int oi[8];
#pragma unroll
      for (int q = 0; q < 8; ++q) { os[q] = __shfl_xor(ms[q], mask); oi[q] = __shfl_xor(mi[q], mask); }
#pragma unroll
      for (int q = 0; q < 8; ++q) ins8(os[q], oi[q], ms, mi);
    }
    if (t == 0) {
#pragma unroll
      for (int q = 0; q < 8; ++q) g8[q] = mi[q];
    }
  }
  __syncthreads();

  {
    const int c = t >> 5, g = t & 31;
    const int id = g8[c];
    float ssq = 0.0f, dt = 0.0f;
    if (id < M_TOT) {
      const float4* bp = reinterpret_cast<const float4*>(bank + (size_t)id * 256);
      const float4 x0 = bp[g * 2], x1 = bp[g * 2 + 1];
      const float4 r0v = *reinterpret_cast<const float4*>(&rnL[g * 8]);
      const float4 r1v = *reinterpret_cast<const float4*>(&rnL[g * 8 + 4]);
      ssq = x0.x*x0.x + x0.y*x0.y + x0.z*x0.z + x0.w*x0.w +
            x1.x*x1.x + x1.y*x1.y + x1.z*x1.z + x1.w*x1.w;
      dt  = x0.x*r0v.x + x0.y*r0v.y + x0.z*r0v.z + x0.w*r0v.w +
            x1.x*r1v.x + x1.y*r1v.y + x1.z*r1v.z + x1.w*r1v.w;
    }
#pragma unroll
    for (int mask = 1; mask < 32; mask <<= 1) { ssq += __shfl_xor(ssq, mask); dt += __shfl_xor(dt, mask); }
    if (g == 0)
      sc8[c] = (id < M_TOT)
                 ? dt * (1.0f / fmaxf(sqrtf(ssq), 1e-12f)) * (vals[id] + 1e-8f)
                 : -INFINITY;
  }
  __syncthreads();

  if (t == 0) {
    float gs[3] = {-INFINITY, -INFINITY, -INFINITY};
    int gi[3] = {0x7fffffff, 0x7ffffffe, 0x7ffffffd};
#pragma unroll
    for (int q = 0; q < 8; ++q) ins3(sc8[q], g8[q], gs, gi);
    gidx[0] = gi[0]; gidx[1] = gi[1]; gidx[2] = gi[2];
  }
  __syncthreads();

  const int i0 = gidx[0], i1 = gidx[1], i2 = gidx[2];
  const float retr = (bank[(size_t)i0 * 256 + t] + bank[(size_t)i1 * 256 + t] +
                      bank[(size_t)i2 * 256 + t]) / 3.0f;
  rfused[b * 256 + t] = 0.5f * r0[b * 256 + t] + 0.5f * retr;
}

// ---------------------------------------------------------------- policy heads (+threefry categorical)
__global__ __launch_bounds__(256)
void heads(const float* __restrict__ rf, const float* __restrict__ Wc, const float* __restrict__ bc,
           const float* __restrict__ Wd, const float* __restrict__ bd,
           const float* __restrict__ Wsw, const float* __restrict__ bsw,
           const float* __restrict__ Wv, const float* __restrict__ bv,
           float* __restrict__ out) {
  const int b = blockIdx.x, t = threadIdx.x;
  __shared__ float rl[256];
  __shared__ float red[256];
  __shared__ float hd[8];
  rl[t] = rf[b * 256 + t];
  __syncthreads();
  float y = bd[t];
#pragma unroll 8
  for (int k = 0; k < 256; ++k) y += rl[k] * Wd[k * 256 + t];
  red[t] = y * y;
  if (t < 4) {
    float a;
    if (t == 0) { a = bc[0]; for (int k = 0; k < 256; ++k) a += rl[k] * Wc[2 * k]; }
    else if (t == 1) { a = bc[1]; for (int k = 0; k < 256; ++k) a += rl[k] * Wc[2 * k + 1]; }
    else if (t == 2) { a = bsw[0]; for (int k = 0; k < 256; ++k) a += rl[k] * Wsw[k]; }
    else { a = bv[0]; for (int k = 0; k < 256; ++k) a += rl[k] * Wv[k]; }
    hd[t] = a;
  }
  __syncthreads();
  for (int s = 128; s > 0; s >>= 1) { if (t < s) red[t] += red[t + s]; __syncthreads(); }
  const float dirn = y / fmaxf(sqrtf(red[0]), 1e-12f);
  if (t == 0) {
    const float l0 = hd[0], l1 = hd[1];
    uint32_t a0, a1, c0, c1;
    threefry2x32(0u, 1u, 0u, (uint32_t)(2 * b), a0, a1);
    threefry2x32(0u, 1u, 0u, (uint32_t)(2 * b + 1), c0, c1);
    const float g0 = gumbel_from_bits(a0 ^ a1);
    const float g1 = gumbel_from_bits(c0 ^ c1);
    const int act = (l1 + g1 > l0 + g0) ? 1 : 0;
    const float mx = fmaxf(l0, l1);
    const float lse = mx + logf(expf(l0 - mx) + expf(l1 - mx));
    const float lp0 = l0 - lse, lp1 = l1 - lse;
    out[OFF_ACT + b] = (float)act;
    out[OFF_LP + b] = act ? lp1 : lp0;
    out[OFF_VAL + b] = hd[3];
    out[OFF_ENT + b] = -(expf(lp0) * lp0 + expf(lp1) * lp1);
    hd[4] = 2.0f / (1.0f + expf(-hd[2]));
  }
  __syncthreads();
  out[OFF_POS + b * 256 + t] = rl[t] + hd[4] * dirn;
}

// ---------------------------------------------------------------- launch
extern "C" void kernel_launch(void* const* d_in, const int* in_sizes, int n_in,
                              void* d_out, int out_size, void* d_ws, size_t ws_size,
                              hipStream_t stream) {
  const float* state = (const float*)d_in[0];
  const float* bank  = (const float*)d_in[1];
  const float* vals  = (const float*)d_in[2];
  const float* W1  = (const float*)d_in[3];
  const float* b1  = (const float*)d_in[4];
  const float* W2  = (const float*)d_in[5];
  const float* b2  = (const float*)d_in[6];
  const float* Wc  = (const float*)d_in[7];
  const float* bc  = (const float*)d_in[8];
  const float* Wd  = (const float*)d_in[9];
  const float* bd  = (const float*)d_in[10];
  const float* Wsw = (const float*)d_in[11];
  const float* bsw = (const float*)d_in[12];
  const float* Wv  = (const float*)d_in[13];
  const float* bv  = (const float*)d_in[14];
  const float* T1w = (const float*)d_in[15];
  const float* t1b = (const float*)d_in[16];
  const float* T2w = (const float*)d_in[17];
  const float* t2b = (const float*)d_in[18];
  float* out = (float*)d_out;
  float* ws = (float*)d_ws;

  // workspace layout (floats). regA (W1/T2 partial region, 1048576 floats) is
  // dead between combine_h1 and the T2 gemm, so cand buffers overlap it:
  //   sims writes cs/ci after combine_h1, merge consumes them before T2 runs.
  float* regA = ws;                   // 1048576: W1 partials (8x131072) / T2 partials (2x524288)
  float* cs   = ws;                   // 500224 (128*977*4)  [overlaps regA]
  int*   ci   = (int*)(ws + 500224);  // 500224              [overlaps regA]
  float* h1   = ws + 1048576;         // 131072
  float* regC = ws + 1179648;         // 262144: W2 partials (8x32768) / T1 partials (2x131072)
  float* r0   = ws + 1441792;         // 32768
  float* rnm  = ws + 1474560;         // 32768
  float* rf   = ws + 1507328;         // 32768
  float* h2   = ws + 1540096;         // 131072

  // state_projection: H -> H/4 (relu) -> R
  gemm_tile<<<dim3(16, 2, 8), 256, 0, stream>>>(state, W1, regA, 128, 1024, 4096, 512);
  combine_z<8, true><<<512, 256, 0, stream>>>(regA, b1, h1, 131072, 1023);
  gemm_tile<<<dim3(4, 2, 8), 256, 0, stream>>>(h1, W2, regC, 128, 256, 1024, 128);
  combine_r0<<<128, 256, 0, stream>>>(regC, b2, r0, rnm);
  // retrieval: MFMA approx sims + per-chunk top-4, then exact-rescore merge + fuse
  sims_topk<<<NCHUNK, 256, 0, stream>>>(rnm, bank, vals, cs, ci);
  topk_merge_fuse<<<128, 256, 0, stream>>>(cs, ci, bank, vals, rnm, r0, rf);
  // policy heads + position
  heads<<<128, 256, 0, stream>>>(rf, Wc, bc, Wd, bd, Wsw, bsw, Wv, bv, out);
  // thought_projection: R -> H/4 (relu) -> H
  gemm_tile<<<dim3(16, 2, 2), 256, 0, stream>>>(out + OFF_POS, T1w, regC, 128, 1024, 256, 128);
  combine_z<2, true><<<512, 256, 0, stream>>>(regC, t1b, h2, 131072, 1023);
  gemm_tile<<<dim3(64, 2, 2), 256, 0, stream>>>(h2, T2w, regA, 128, 4096, 1024, 512);
  combine_z<2, false><<<2048, 256, 0, stream>>>(regA, t2b, out + OFF_LATENT, 524288, 4095);
}